// Round 1
// 10815.574 us; speedup vs baseline: 1.0615x; 1.0615x over previous
//
#include <hip/hip_runtime.h>
#include <stdint.h>

#define HH 256
#define BB 64
#define TT 1024
#define G4H 1024
#define NSL 16              // workgroups per direction (gate-split)
#define KC 16               // h-columns owned per WG
#define SPIN_LIM (1 << 24)  // cumulative spin budget -> deadlock = fast wrong answer
#define TCHUNK 64           // t-steps per gx1_gemm block

typedef _Float16 v8h __attribute__((ext_vector_type(8)));
typedef float v4f __attribute__((ext_vector_type(4)));

union HFP8 { _Float16 h[8]; v8h v; };
union ULL2F { unsigned long long u[2]; v8h v; };
union ULLH4 { unsigned long long u; _Float16 h[4]; };

__device__ __forceinline__ float fsig(float x) {
  float e = __builtin_amdgcn_exp2f(x * -1.44269504f);
  return __builtin_amdgcn_rcpf(1.f + e);
}
__device__ __forceinline__ float ftanh(float x) {
  float e = __builtin_amdgcn_exp2f(x * 2.88539008f);
  return 1.f - 2.f * __builtin_amdgcn_rcpf(e + 1.f);
}

// ---------------- prep kernels ----------------
__global__ void prep_w1(const float* __restrict__ w, _Float16* __restrict__ wh) {
  int i = blockIdx.x * 256 + threadIdx.x;
  if (i < 2 * 1024 * 512) wh[i] = (_Float16)w[i];
}

// xpad[d][t][b][32] fp16 : x (or reversed x) padded to K=32
__global__ void prep_x(const float* __restrict__ x, const int* __restrict__ lengths,
                       _Float16* __restrict__ xpad) {
  int i = blockIdx.x * 256 + threadIdx.x;
  if (i >= 2 * TT * BB * 32) return;
  int k = i & 31, bb = (i >> 5) & 63, t = (i >> 11) & 1023, d = (i >> 21) & 1;
  float v = 0.f;
  if (k < 3) {
    int L = lengths[bb];
    int rt = (d == 0) ? t : ((t < L) ? (L - 1 - t) : t);
    v = x[((size_t)bb * TT + rt) * 3 + k];
  }
  xpad[i] = (_Float16)v;
}

// ---------------- layer-1 gate-init GEMM (hoisted out of the scan) ----------------
// gx1[d][t][gate][b] = (h1[b, rta(d,t,b), :] @ W_ih_l1[d]^T)[gate], fp16.
// grid: 2 dirs * 16 col-slices * 16 t-chunks = 512 blocks of 256 threads.
// W-fragments register-resident (same B-layout as the scan); per t: 16 A-loads + 64 MFMA.
// This kernel has real parallelism (512 blocks), so the L3 latency that made the
// in-scan gate-init cost ~10k cycles/step is hidden by TLP here.
__global__ __launch_bounds__(256, 1)
void gx1_gemm(const _Float16* __restrict__ h1, const _Float16* __restrict__ w1h,
              const int* __restrict__ lengths, _Float16* __restrict__ gxq) {
  const int blk = blockIdx.x;
  const int d = blk & 1;
  const int g = (blk >> 1) & 15;
  const int tc = blk >> 5;  // 0..15
  const int tid = threadIdx.x;
  const int w = tid >> 6;
  const int l = tid & 63;
  const int l15 = l & 15;
  const int hp = l >> 4;
  const int col = g * KC + l15;

  // B-fragments: W_ih_l1 rows {nt*256+col}, K=512
  v8h wf[16][4];
#pragma unroll
  for (int kt = 0; kt < 16; ++kt)
#pragma unroll
    for (int nt = 0; nt < 4; ++nt)
      wf[kt][nt] =
          *(const v8h*)(w1h + ((size_t)d * G4H + nt * HH + col) * 512 + kt * 32 + hp * 8);

  const int b = w * 16 + l15;  // this lane's A-row (batch)
  const int L = lengths[b];
  const _Float16* hb = h1 + (size_t)b * TT * 512;

  for (int t = tc * TCHUNK; t < tc * TCHUNK + TCHUNK; ++t) {
    const int rta = (d == 0) ? t : ((t < L) ? (L - 1 - t) : t);
    const _Float16* arow = hb + (size_t)rta * 512;
    v4f acc[4];
#pragma unroll
    for (int nt = 0; nt < 4; ++nt) acc[nt] = v4f{0.f, 0.f, 0.f, 0.f};
#pragma unroll
    for (int kt = 0; kt < 16; ++kt) {
      const v8h a = *(const v8h*)(arow + kt * 32 + hp * 8);
#pragma unroll
      for (int nt = 0; nt < 4; ++nt)
        acc[nt] = __builtin_amdgcn_mfma_f32_16x16x32_f16(a, wf[kt][nt], acc[nt], 0, 0, 0);
    }
    // C-frag: row(b') = w*16 + hp*4 + r, col(gate) = nt*256 + col -> one 8B store per nt
    _Float16* drow = gxq + (((size_t)d * TT + t) * G4H) * (size_t)BB + w * 16 + hp * 4;
#pragma unroll
    for (int nt = 0; nt < 4; ++nt) {
      ULLH4 p;
#pragma unroll
      for (int r = 0; r < 4; ++r) p.h[r] = (_Float16)acc[nt][r];
      *(unsigned long long*)(drow + (size_t)(nt * HH + col) * BB) = p.u;
    }
  }
}

// ---------------- persistent gate-split LSTM scan ----------------
// grid 128; active blocks: (blk&7)<2 -> dir d = blk&7, slice g = blk>>3 (0..15).
// WG owns h-cols [g*16,g*16+16) -> gate rows {nt*256 + g*16 + l15}.
// Cross-WG exchange uses ONLY relaxed agent-scope atomics. Ordering:
// stores -> s_waitcnt vmcnt(0) -> __syncthreads -> tid0 publishes progress word.
// LAYER==1: gate-init comes from precomputed gxq (4x8B loads) when available;
// falls back to the in-scan h1in GEMM when gxq==nullptr (workspace too small).
template <int LAYER>
__global__ __launch_bounds__(256, 1)
void lstm_scan(const float* __restrict__ Whh, const float* __restrict__ Wih0,
               const float* __restrict__ bih, const float* __restrict__ bhh,
               const _Float16* __restrict__ xpad, const _Float16* __restrict__ h1in,
               const _Float16* __restrict__ w1h, const _Float16* __restrict__ gxq,
               _Float16* __restrict__ h1out, float* __restrict__ feat,
               short* __restrict__ h_ex, int* __restrict__ prog,
               const int* __restrict__ lengths) {
  const int blk = blockIdx.x;
  if ((blk & 7) >= 2) return;
  const int d = blk & 7;
  const int g = blk >> 3;
  const int tid = threadIdx.x;
  const int w = tid >> 6;        // wave id = batch tile
  const int l = tid & 63;
  const int l15 = l & 15;
  const int hp = l >> 4;
  const int col = g * KC + l15;  // owned h-column

  __shared__ int s_ok;

  // persistent W_hh fragments (B-operand layout: lane = W[j=nt*256+col][k=kt*32+hp*8+e])
  v8h wfrag[8][4];
#pragma unroll
  for (int kt = 0; kt < 8; ++kt) {
#pragma unroll
    for (int nt = 0; nt < 4; ++nt) {
      const int j = nt * HH + col;
      const float* src = Whh + ((size_t)d * G4H + j) * HH + kt * 32 + hp * 8;
      HFP8 p;
#pragma unroll
      for (int e = 0; e < 8; ++e) p.h[e] = (_Float16)src[e];
      wfrag[kt][nt] = p.v;
    }
  }
  float bias[4];
#pragma unroll
  for (int nt = 0; nt < 4; ++nt)
    bias[nt] = bih[d * G4H + nt * HH + col] + bhh[d * G4H + nt * HH + col];

  v8h xfrag[4];  // layer 0: W_ih_l0 (K=3 padded to 32)
  if (LAYER == 0) {
#pragma unroll
    for (int nt = 0; nt < 4; ++nt) {
      const int j = nt * HH + col;
      HFP8 p;
#pragma unroll
      for (int e = 0; e < 8; ++e) {
        const int kl = hp * 8 + e;
        p.h[e] = (kl < 3) ? (_Float16)Wih0[((size_t)d * G4H + j) * 3 + kl] : (_Float16)0.f;
      }
      xfrag[nt] = p.v;
    }
  }
  v8h w1frag[16][4];  // layer 1 FALLBACK: W_ih_l1 slice, B-fragments (K=512)
  if (LAYER == 1 && gxq == nullptr) {
#pragma unroll
    for (int kt = 0; kt < 16; ++kt)
#pragma unroll
      for (int nt = 0; nt < 4; ++nt)
        w1frag[kt][nt] =
            *(const v8h*)(w1h + ((size_t)d * G4H + nt * HH + col) * 512 + kt * 32 + hp * 8);
  }

  int Lr[4];
#pragma unroll
  for (int r = 0; r < 4; ++r) Lr[r] = lengths[w * 16 + hp * 4 + r];
  const int La = lengths[w * 16 + l15];  // this lane's A-row length (layer-1 fallback)

  float c_reg[4] = {0.f, 0.f, 0.f, 0.f};
  float h_reg[4] = {0.f, 0.f, 0.f, 0.f};

  short* hex_d = h_ex + (size_t)d * 2 * BB * HH;   // parity-double-buffered
  int* prg = prog + d * NSL * 16;                  // progress words, 64B padded
  int guard = 0;

  for (int t = 0; t < TT; ++t) {
    v4f acc[4];
#pragma unroll
    for (int nt = 0; nt < 4; ++nt) acc[nt] = v4f{bias[nt], bias[nt], bias[nt], bias[nt]};

    if (LAYER == 0) {  // x contribution: plain cached loads (read-only data)
      const v8h a = *(const v8h*)(xpad + (((size_t)d * TT + t) * BB + w * 16 + l15) * 32 + hp * 8);
#pragma unroll
      for (int nt = 0; nt < 4; ++nt)
        acc[nt] = __builtin_amdgcn_mfma_f32_16x16x32_f16(a, xfrag[nt], acc[nt], 0, 0, 0);
    } else if (gxq != nullptr) {
      // gate-init precomputed: 4 x 8B loads (issued before the wait -> overlaps poll)
      const _Float16* gp =
          gxq + (((size_t)d * TT + t) * G4H) * (size_t)BB + w * 16 + hp * 4;
#pragma unroll
      for (int nt = 0; nt < 4; ++nt) {
        ULLH4 p;
        p.u = *(const unsigned long long*)(gp + (size_t)(nt * HH + col) * BB);
#pragma unroll
        for (int r = 0; r < 4; ++r) acc[nt][r] += (float)p.h[r];
      }
    } else {
      // FALLBACK: gate-init = h1r @ W_ih1^T in-scan (old path)
      const int rta = (d == 0) ? t : ((t < La) ? (La - 1 - t) : t);
      const _Float16* arow = h1in + ((size_t)(w * 16 + l15) * TT + rta) * 512;
#pragma unroll
      for (int kt = 0; kt < 16; ++kt) {
        const v8h a = *(const v8h*)(arow + kt * 32 + hp * 8);
#pragma unroll
        for (int nt = 0; nt < 4; ++nt)
          acc[nt] = __builtin_amdgcn_mfma_f32_16x16x32_f16(a, w1frag[kt][nt], acc[nt], 0, 0, 0);
      }
    }

    if (t > 0) {
      if (w == 0) {  // wave 0: 16 lanes poll the 16 progress words (coalesced round)
        int ok = 1;
        for (;;) {
          int v = (l < NSL)
                      ? __hip_atomic_load(&prg[l * 16], __ATOMIC_RELAXED, __HIP_MEMORY_SCOPE_AGENT)
                      : (t - 1);
          if (__all(v >= t - 1)) break;
          __builtin_amdgcn_s_sleep(1);
          if (++guard > SPIN_LIM) { ok = 0; break; }
        }
        if (l == 0) s_ok = ok;
      }
      __syncthreads();              // publishes s_ok; others waited here during spin
      if (!s_ok) break;             // watchdog: deadlock -> fast wrong answer, no hang

      // A-fragments straight from exchange buffer: 16 x 8B relaxed-atomic loads
      const unsigned long long* src =
          (const unsigned long long*)(hex_d + ((t - 1) & 1) * BB * HH);
      const int base = (w * 16 + l15) * 64 + hp * 2;  // ull index into 256-col row
      unsigned long long fr[16];
#pragma unroll
      for (int kt = 0; kt < 8; ++kt) {
        fr[2 * kt] = __hip_atomic_load(src + base + kt * 8, __ATOMIC_RELAXED,
                                       __HIP_MEMORY_SCOPE_AGENT);
        fr[2 * kt + 1] = __hip_atomic_load(src + base + kt * 8 + 1, __ATOMIC_RELAXED,
                                           __HIP_MEMORY_SCOPE_AGENT);
      }
#pragma unroll
      for (int kt = 0; kt < 8; ++kt) {
        ULL2F u;
        u.u[0] = fr[2 * kt];
        u.u[1] = fr[2 * kt + 1];
#pragma unroll
        for (int nt = 0; nt < 4; ++nt)
          acc[nt] = __builtin_amdgcn_mfma_f32_16x16x32_f16(u.v, wfrag[kt][nt], acc[nt], 0, 0, 0);
      }
    }

    short* dst = hex_d + (t & 1) * BB * HH;
#pragma unroll
    for (int r = 0; r < 4; ++r) {
      const int m = w * 16 + hp * 4 + r;
      const float iv = acc[0][r], fv = acc[1][r], gv = acc[2][r], ov = acc[3][r];
      const float cn = fsig(fv) * c_reg[r] + fsig(iv) * ftanh(gv);
      const float hn = fsig(ov) * ftanh(cn);
      const bool valid = t < Lr[r];
      if (valid) { c_reg[r] = cn; h_reg[r] = hn; }
      union { _Float16 f; short s; } hb;
      hb.f = (_Float16)h_reg[r];
      __hip_atomic_store(&dst[m * HH + col], hb.s, __ATOMIC_RELAXED, __HIP_MEMORY_SCOPE_AGENT);
      if (LAYER == 0) {
        const int tout = (d == 0) ? t : (valid ? (Lr[r] - 1 - t) : t);
        h1out[((size_t)m * TT + tout) * 512 + d * HH + col] =
            valid ? (_Float16)h_reg[r] : (_Float16)0.f;
      } else if (d == 1 && t == 0) {
        feat[m * 512 + HH + col] = h_reg[r];  // bwd out at orig t=L-1 == first bwd step
      }
    }
    asm volatile("s_waitcnt vmcnt(0)" ::: "memory");  // my exchange stores are at L3
    __syncthreads();                                   // => all WG stores are at L3
    if (tid == 0)
      __hip_atomic_store(&prg[g * 16], t, __ATOMIC_RELAXED, __HIP_MEMORY_SCOPE_AGENT);
  }
  if (LAYER == 1 && d == 0) {  // fwd final state (frozen at t=L-1)
#pragma unroll
    for (int r = 0; r < 4; ++r) feat[(w * 16 + hp * 4 + r) * 512 + col] = h_reg[r];
  }
}

// ---------------- head ----------------
__global__ void head_fc1(const float* __restrict__ feat, const float* __restrict__ w,
                         const float* __restrict__ b, float* __restrict__ y) {
  const int bb = blockIdx.x, o = threadIdx.x;
  __shared__ float f[512];
  f[o] = feat[bb * 512 + o];
  f[o + 256] = feat[bb * 512 + 256 + o];
  __syncthreads();
  float acc = b[o];
  const float* wr = w + (size_t)o * 512;
  for (int i = 0; i < 512; ++i) acc = fmaf(f[i], wr[i], acc);
  y[bb * 256 + o] = fmaxf(acc, 0.f);
}
__global__ void head_bn(const float* __restrict__ y, const float* __restrict__ gamma,
                        const float* __restrict__ beta, float* __restrict__ ss) {
  const int o = threadIdx.x;
  float s1 = 0.f, s2 = 0.f;
  for (int b = 0; b < 64; ++b) { const float v = y[b * 256 + o]; s1 += v; s2 += v * v; }
  const float mean = s1 * 0.015625f;
  const float var = s2 * 0.015625f - mean * mean;
  const float sc = gamma[o] * __builtin_amdgcn_rsqf(var + 1e-5f);
  ss[o] = sc;
  ss[256 + o] = beta[o] - mean * sc;
}
__global__ void head_out(const float* __restrict__ y, const float* __restrict__ ss,
                         const float* __restrict__ w, const float* __restrict__ b,
                         float* __restrict__ out) {
  const int bb = blockIdx.x, q = threadIdx.x;
  __shared__ float z[256];
  z[q] = y[bb * 256 + q] * ss[q] + ss[256 + q];
  __syncthreads();
  if (q < 196) {
    float acc = b[q];
    const float* wr = w + (size_t)q * 256;
    for (int o = 0; o < 256; ++o) acc = fmaf(z[o], wr[o], acc);
    out[bb * 196 + q] = acc;
  }
}

extern "C" void kernel_launch(void* const* d_in, const int* in_sizes, int n_in,
                              void* d_out, int out_size, void* d_ws, size_t ws_size,
                              hipStream_t stream) {
  const float* x       = (const float*)d_in[0];
  const int* lengths   = (const int*)d_in[1];
  const float* W_ih_l0 = (const float*)d_in[2];
  const float* W_hh_l0 = (const float*)d_in[3];
  const float* b_ih_l0 = (const float*)d_in[4];
  const float* b_hh_l0 = (const float*)d_in[5];
  const float* W_ih_l1 = (const float*)d_in[6];
  const float* W_hh_l1 = (const float*)d_in[7];
  const float* b_ih_l1 = (const float*)d_in[8];
  const float* b_hh_l1 = (const float*)d_in[9];
  const float* fc1_w   = (const float*)d_in[10];
  const float* fc1_b   = (const float*)d_in[11];
  const float* bn_g    = (const float*)d_in[12];
  const float* bn_b    = (const float*)d_in[13];
  const float* fco_w   = (const float*)d_in[14];
  const float* fco_b   = (const float*)d_in[15];
  float* out = (float*)d_out;

  char* ws = (char*)d_ws;
  size_t off = 0;
  auto alloc = [&](size_t sz) { char* p = ws + off; off += (sz + 255) & ~(size_t)255; return p; };
  int* prog0       = (int*)alloc(2 * NSL * 16 * 4);   // per-WG progress words, 64B padded
  int* prog1       = (int*)alloc(2 * NSL * 16 * 4);
  float* feat      = (float*)alloc(BB * 512 * 4);
  float* ybuf      = (float*)alloc(BB * 256 * 4);
  float* ss        = (float*)alloc(2 * 256 * 4);
  short* h_ex      = (short*)alloc(2 * 2 * BB * HH * 2);
  _Float16* w1h    = (_Float16*)alloc((size_t)2 * 1024 * 512 * 2);
  _Float16* xpad   = (_Float16*)alloc((size_t)2 * TT * BB * 32 * 2);
  _Float16* h1     = (_Float16*)alloc((size_t)BB * TT * 512 * 2);
  // base total ~74.3 MB

  if (off > ws_size) {  // distinct signal: NaN output instead of zeros
    hipMemsetAsync(d_out, 0xFF, (size_t)out_size * 4, stream);
    return;
  }

  // layer-1 gate-init buffer: gx1[d][t][gate][b] fp16, 256 MB. Graceful fallback
  // to in-scan gate-init if the workspace can't hold it.
  const size_t gx_bytes = (size_t)2 * TT * G4H * BB * 2;
  _Float16* gxq = nullptr;
  if (off + gx_bytes + 256 <= ws_size) gxq = (_Float16*)alloc(gx_bytes);

  hipMemsetAsync(prog0, 0xFF, 2 * 2 * NSL * 16 * 4, stream);  // prog = -1 (contiguous)

  prep_w1<<<(2 * 1024 * 512 + 255) / 256, 256, 0, stream>>>(W_ih_l1, w1h);
  prep_x<<<(2 * TT * BB * 32 + 255) / 256, 256, 0, stream>>>(x, lengths, xpad);

  lstm_scan<0><<<128, 256, 0, stream>>>(W_hh_l0, W_ih_l0, b_ih_l0, b_hh_l0, xpad, nullptr,
                                        nullptr, nullptr, h1, nullptr, h_ex, prog0, lengths);
  if (gxq)
    gx1_gemm<<<512, 256, 0, stream>>>(h1, w1h, lengths, gxq);
  lstm_scan<1><<<128, 256, 0, stream>>>(W_hh_l1, nullptr, b_ih_l1, b_hh_l1, nullptr, h1,
                                        w1h, gxq, nullptr, feat, h_ex, prog1, lengths);

  head_fc1<<<64, 256, 0, stream>>>(feat, fc1_w, fc1_b, ybuf);
  head_bn<<<1, 256, 0, stream>>>(ybuf, bn_g, bn_b, ss);
  head_out<<<64, 256, 0, stream>>>(ybuf, ss, fco_w, fco_b, out);
}

// Round 6
// 8821.239 us; speedup vs baseline: 1.3015x; 1.2261x over previous
//
#include <hip/hip_runtime.h>
#include <stdint.h>

#define HH 256
#define BB 64
#define TT 1024
#define G4H 1024
#define NSL 16              // workgroups per direction (gate-split)
#define KC 16               // h-columns owned per WG
#define SPIN_LIM (1 << 21)  // spin budget: ~100ms worst case -> fast wrong answer, never a bench timeout
#define TCHUNK 64           // t-steps per gx1_gemm block

typedef _Float16 v8h __attribute__((ext_vector_type(8)));
typedef float v4f __attribute__((ext_vector_type(4)));

union HFP8 { _Float16 h[8]; v8h v; };
union ULL2F { unsigned long long u[2]; v8h v; };

__device__ __forceinline__ float fsig(float x) {
  float e = __builtin_amdgcn_exp2f(x * -1.44269504f);
  return __builtin_amdgcn_rcpf(1.f + e);
}
__device__ __forceinline__ float ftanh(float x) {
  float e = __builtin_amdgcn_exp2f(x * 2.88539008f);
  return 1.f - 2.f * __builtin_amdgcn_rcpf(e + 1.f);
}

// ---------------- prep kernels ----------------
__global__ void prep_w1(const float* __restrict__ w, _Float16* __restrict__ wh) {
  int i = blockIdx.x * 256 + threadIdx.x;
  if (i < 2 * 1024 * 512) wh[i] = (_Float16)w[i];
}

// xpad[d][t][b][32] fp16 : x (or reversed x) padded to K=32
__global__ void prep_x(const float* __restrict__ x, const int* __restrict__ lengths,
                       _Float16* __restrict__ xpad) {
  int i = blockIdx.x * 256 + threadIdx.x;
  if (i >= 2 * TT * BB * 32) return;
  int k = i & 31, bb = (i >> 5) & 63, t = (i >> 11) & 1023, d = (i >> 21) & 1;
  float v = 0.f;
  if (k < 3) {
    int L = lengths[bb];
    int rt = (d == 0) ? t : ((t < L) ? (L - 1 - t) : t);
    v = x[((size_t)bb * TT + rt) * 3 + k];
  }
  xpad[i] = (_Float16)v;
}

// ---------------- layer-1 gate-init GEMM (hoisted, PHASED, fp32 out) ----------------
// h1 layout [t][d][b][256] in SCAN-STEP order (bwd not re-reversed). Input row of
// layer-1 dir d at scan step t = [h1[p][0][b], h1[s][1][b]] with
// p = (d==0)? t : ((t<L)? L-1-t : t),  s = (p<L)? L-1-p : p   (for d==1, s==t).
// Output gxq[tloc][d][gate][b] fp32 for t in [t0, t0 + 64*gridT).
__global__ __launch_bounds__(256, 1)
void gx1_gemm(const _Float16* __restrict__ h1, const _Float16* __restrict__ w1h,
              const int* __restrict__ lengths, float* __restrict__ gxq, int t0) {
  const int blk = blockIdx.x;
  const int d = blk & 1;
  const int g = (blk >> 1) & 15;
  const int tc = blk >> 5;
  const int tid = threadIdx.x;
  const int w = tid >> 6;
  const int l = tid & 63;
  const int l15 = l & 15;
  const int hp = l >> 4;
  const int col = g * KC + l15;

  // B-fragments: W_ih_l1 rows {nt*256+col}, K=512 (k<256 fwd half, k>=256 bwd half)
  v8h wf[16][4];
#pragma unroll
  for (int kt = 0; kt < 16; ++kt)
#pragma unroll
    for (int nt = 0; nt < 4; ++nt)
      wf[kt][nt] =
          *(const v8h*)(w1h + ((size_t)d * G4H + nt * HH + col) * 512 + kt * 32 + hp * 8);

  const int b = w * 16 + l15;  // this lane's A-row (batch)
  const int L = lengths[b];

  for (int i = 0; i < TCHUNK; ++i) {
    const int t = t0 + tc * TCHUNK + i;
    const int tloc = t - t0;
    const int p = (d == 0) ? t : ((t < L) ? (L - 1 - t) : t);
    const int s = (p < L) ? (L - 1 - p) : p;
    const _Float16* afwd = h1 + (((size_t)p * 2 + 0) * BB + b) * HH + hp * 8;
    const _Float16* abwd = h1 + (((size_t)s * 2 + 1) * BB + b) * HH + hp * 8;
    v4f acc[4];
#pragma unroll
    for (int nt = 0; nt < 4; ++nt) acc[nt] = v4f{0.f, 0.f, 0.f, 0.f};
#pragma unroll
    for (int kt = 0; kt < 8; ++kt) {
      const v8h a = *(const v8h*)(afwd + kt * 32);
#pragma unroll
      for (int nt = 0; nt < 4; ++nt)
        acc[nt] = __builtin_amdgcn_mfma_f32_16x16x32_f16(a, wf[kt][nt], acc[nt], 0, 0, 0);
    }
#pragma unroll
    for (int kt = 8; kt < 16; ++kt) {
      const v8h a = *(const v8h*)(abwd + (kt - 8) * 32);
#pragma unroll
      for (int nt = 0; nt < 4; ++nt)
        acc[nt] = __builtin_amdgcn_mfma_f32_16x16x32_f16(a, wf[kt][nt], acc[nt], 0, 0, 0);
    }
    // C-frag: row(b') = w*16+hp*4+r, col(gate) = nt*256+col -> one 16B store per nt
    float* drow = gxq + (((size_t)tloc * 2 + d) * G4H) * (size_t)BB + w * 16 + hp * 4;
#pragma unroll
    for (int nt = 0; nt < 4; ++nt)
      *(v4f*)(drow + (size_t)(nt * HH + col) * BB) = acc[nt];
  }
}

// ---------------- persistent gate-split LSTM scan ----------------
// grid 128; active blocks: (blk&7)<2 -> dir d = blk&7, slice g = blk>>3 (0..15).
// ROUND-6 BISECT: fast L2 exchange REMOVED — all exchange ops are the round-0/1
// proven agent-scope relaxed atomics. Ordering: h stores -> s_waitcnt vmcnt(0) ->
// __syncthreads -> tid0 publishes progress word.
// GX==1: gate-init from fp32 gxq[tloc][d][gate][b], register-prefetched one step
// ahead. GX==0 (LAYER 1): in-scan gate GEMM fallback reading h1in.
// Phasing (LAYER 1): [t0,t1) window; c/h state carried via cst across launches
// (inter-kernel stream ordering guarantees visibility of h_ex/prog/cst).
template <int LAYER, int GX>
__global__ __launch_bounds__(256, 1)
void lstm_scan(const float* __restrict__ Whh, const float* __restrict__ Wih0,
               const float* __restrict__ bih, const float* __restrict__ bhh,
               const _Float16* __restrict__ xpad, const float* __restrict__ gxq,
               const _Float16* __restrict__ h1in,
               _Float16* __restrict__ h1out, float* __restrict__ feat,
               short* __restrict__ h_ex, int* __restrict__ prog,
               const int* __restrict__ lengths, float* __restrict__ cst,
               int t0, int t1) {
  const int blk = blockIdx.x;
  if ((blk & 7) >= 2) return;
  const int d = blk & 7;
  const int g = blk >> 3;
  const int tid = threadIdx.x;
  const int w = tid >> 6;        // wave id = batch tile
  const int l = tid & 63;
  const int l15 = l & 15;
  const int hp = l >> 4;
  const int col = g * KC + l15;  // owned h-column

  __shared__ int s_ok;

  // persistent W_hh fragments (B-operand layout: lane = W[j=nt*256+col][k=kt*32+hp*8+e])
  v8h wfrag[8][4];
#pragma unroll
  for (int kt = 0; kt < 8; ++kt) {
#pragma unroll
    for (int nt = 0; nt < 4; ++nt) {
      const int j = nt * HH + col;
      const float* src = Whh + ((size_t)d * G4H + j) * HH + kt * 32 + hp * 8;
      HFP8 p;
#pragma unroll
      for (int e = 0; e < 8; ++e) p.h[e] = (_Float16)src[e];
      wfrag[kt][nt] = p.v;
    }
  }
  float bias[4];
#pragma unroll
  for (int nt = 0; nt < 4; ++nt)
    bias[nt] = bih[d * G4H + nt * HH + col] + bhh[d * G4H + nt * HH + col];

  v8h xfrag[4];  // layer 0: W_ih_l0 (K=3 padded to 32)
  if (LAYER == 0) {
#pragma unroll
    for (int nt = 0; nt < 4; ++nt) {
      const int j = nt * HH + col;
      HFP8 p;
#pragma unroll
      for (int e = 0; e < 8; ++e) {
        const int kl = hp * 8 + e;
        p.h[e] = (kl < 3) ? (_Float16)Wih0[((size_t)d * G4H + j) * 3 + kl] : (_Float16)0.f;
      }
      xfrag[nt] = p.v;
    }
  }
  v8h w1frag[16][4];  // layer-1 fallback: W_ih_l1 slice, B-fragments (K=512)
  if (LAYER == 1 && GX == 0) {
#pragma unroll
    for (int kt = 0; kt < 16; ++kt)
#pragma unroll
      for (int nt = 0; nt < 4; ++nt)
        w1frag[kt][nt] =
            *(const v8h*)((const _Float16*)Wih0 +  // reuse Wih0 slot for w1h
                          ((size_t)d * G4H + nt * HH + col) * 512 + kt * 32 + hp * 8);
  }

  int Lr[4];
#pragma unroll
  for (int r = 0; r < 4; ++r) Lr[r] = lengths[w * 16 + hp * 4 + r];
  const int bb = w * 16 + l15;
  const int La = lengths[bb];  // lane's A-row length (fallback path)

  float c_reg[4] = {0.f, 0.f, 0.f, 0.f};
  float h_reg[4] = {0.f, 0.f, 0.f, 0.f};
  if (LAYER == 1 && t0 > 0) {  // phased restore (written by previous launch)
#pragma unroll
    for (int r = 0; r < 4; ++r) {
      const size_t ix = ((size_t)d * BB + (w * 16 + hp * 4 + r)) * HH + col;
      c_reg[r] = cst[ix];
      h_reg[r] = cst[(size_t)2 * BB * HH + ix];
    }
  }

  short* hex_d = h_ex + (size_t)d * 2 * BB * HH;   // parity-double-buffered
  int* prg = prog + d * NSL * 16;                  // progress words, 64B padded
  int guard = 0;

  // prefetch gate-init input for first step
  v8h xr;      // layer 0
  v4f gxr[4];  // layer 1 (GX path, fp32)
  if (LAYER == 0) {
    xr = *(const v8h*)(xpad + (((size_t)d * TT + t0) * BB + bb) * 32 + hp * 8);
  } else if (GX) {
    const float* gp = gxq + ((size_t)0 * 2 + d) * G4H * (size_t)BB + w * 16 + hp * 4;
#pragma unroll
    for (int nt = 0; nt < 4; ++nt)
      gxr[nt] = *(const v4f*)(gp + (size_t)(nt * HH + col) * BB);
  }

  for (int t = t0; t < t1; ++t) {
    v4f acc[4];
#pragma unroll
    for (int nt = 0; nt < 4; ++nt) acc[nt] = v4f{bias[nt], bias[nt], bias[nt], bias[nt]};

    if (LAYER == 0) {
#pragma unroll
      for (int nt = 0; nt < 4; ++nt)
        acc[nt] = __builtin_amdgcn_mfma_f32_16x16x32_f16(xr, xfrag[nt], acc[nt], 0, 0, 0);
    } else if (GX) {
#pragma unroll
      for (int nt = 0; nt < 4; ++nt) acc[nt] += gxr[nt];
    } else {
      // fallback in-scan gate GEMM (independent of recurrence -> before the wait)
      const int p = (d == 0) ? t : ((t < La) ? (La - 1 - t) : t);
      const int s = (p < La) ? (La - 1 - p) : p;
      const _Float16* afwd = h1in + (((size_t)p * 2 + 0) * BB + bb) * HH + hp * 8;
      const _Float16* abwd = h1in + (((size_t)s * 2 + 1) * BB + bb) * HH + hp * 8;
#pragma unroll
      for (int kt = 0; kt < 8; ++kt) {
        const v8h a = *(const v8h*)(afwd + kt * 32);
#pragma unroll
        for (int nt = 0; nt < 4; ++nt)
          acc[nt] = __builtin_amdgcn_mfma_f32_16x16x32_f16(a, w1frag[kt][nt], acc[nt], 0, 0, 0);
      }
#pragma unroll
      for (int kt = 8; kt < 16; ++kt) {
        const v8h a = *(const v8h*)(abwd + (kt - 8) * 32);
#pragma unroll
        for (int nt = 0; nt < 4; ++nt)
          acc[nt] = __builtin_amdgcn_mfma_f32_16x16x32_f16(a, w1frag[kt][nt], acc[nt], 0, 0, 0);
      }
    }

    if (t > 0) {
      if (w == 0) {  // wave 0: 16 lanes poll the 16 progress words (agent atomics)
        int ok = 1;
        for (;;) {
          int v = (l < NSL)
                      ? __hip_atomic_load(&prg[l * 16], __ATOMIC_RELAXED, __HIP_MEMORY_SCOPE_AGENT)
                      : (t - 1);
          if (__all(v >= t - 1)) break;
          __builtin_amdgcn_s_sleep(1);
          if (++guard > SPIN_LIM) { ok = 0; break; }
        }
        if (l == 0) s_ok = ok;
      }
      __syncthreads();              // publishes s_ok; others waited here during spin
      if (!s_ok) break;             // watchdog: deadlock -> fast wrong answer, no hang

      // A-fragments from exchange buffer: 16 x 8B relaxed-atomic loads
      const unsigned long long* src =
          (const unsigned long long*)(hex_d + ((t - 1) & 1) * BB * HH);
      const int base = (w * 16 + l15) * 64 + hp * 2;  // ull index into 256-col row
      unsigned long long fr[16];
#pragma unroll
      for (int kt = 0; kt < 8; ++kt) {
        fr[2 * kt] = __hip_atomic_load(src + base + kt * 8, __ATOMIC_RELAXED,
                                       __HIP_MEMORY_SCOPE_AGENT);
        fr[2 * kt + 1] = __hip_atomic_load(src + base + kt * 8 + 1, __ATOMIC_RELAXED,
                                           __HIP_MEMORY_SCOPE_AGENT);
      }
#pragma unroll
      for (int kt = 0; kt < 8; ++kt) {
        ULL2F u;
        u.u[0] = fr[2 * kt];
        u.u[1] = fr[2 * kt + 1];
#pragma unroll
        for (int nt = 0; nt < 4; ++nt)
          acc[nt] = __builtin_amdgcn_mfma_f32_16x16x32_f16(u.v, wfrag[kt][nt], acc[nt], 0, 0, 0);
      }
    }

    short* dst = hex_d + (t & 1) * BB * HH;
#pragma unroll
    for (int r = 0; r < 4; ++r) {
      const int m = w * 16 + hp * 4 + r;
      const float iv = acc[0][r], fv = acc[1][r], gv = acc[2][r], ov = acc[3][r];
      const float cn = fsig(fv) * c_reg[r] + fsig(iv) * ftanh(gv);
      const float hn = fsig(ov) * ftanh(cn);
      const bool valid = t < Lr[r];
      if (valid) { c_reg[r] = cn; h_reg[r] = hn; }
      union { _Float16 f; short s; } hb;
      hb.f = (_Float16)h_reg[r];
      __hip_atomic_store(&dst[m * HH + col], hb.s, __ATOMIC_RELAXED, __HIP_MEMORY_SCOPE_AGENT);
      if (LAYER == 1 && d == 1 && t == 0) {
        feat[m * 512 + HH + col] = h_reg[r];  // bwd out at orig t=L-1 == first bwd step
      }
    }
    asm volatile("s_waitcnt vmcnt(0)" ::: "memory");  // my exchange stores are at L3
    __syncthreads();                                   // => all WG stores are at L3
    if (tid == 0)
      __hip_atomic_store(&prg[g * 16], t, __ATOMIC_RELAXED, __HIP_MEMORY_SCOPE_AGENT);

    // ---- post-publish (off the protocol critical path) ----
    if (LAYER == 0) {  // h1 store, coalesced [t][d][b][256], scan-step order
      _Float16* hr = h1out + (((size_t)t * 2 + d) * BB) * HH + col;
#pragma unroll
      for (int r = 0; r < 4; ++r)
        hr[(size_t)(w * 16 + hp * 4 + r) * HH] =
            (t < Lr[r]) ? (_Float16)h_reg[r] : (_Float16)0.f;
    }
    // next-step gate-init prefetch (flies during the next poll window)
    const int tp = (t + 1 < t1) ? t + 1 : t;
    if (LAYER == 0) {
      xr = *(const v8h*)(xpad + (((size_t)d * TT + tp) * BB + bb) * 32 + hp * 8);
    } else if (GX) {
      const float* gp =
          gxq + (((size_t)(tp - t0) * 2 + d) * G4H) * (size_t)BB + w * 16 + hp * 4;
#pragma unroll
      for (int nt = 0; nt < 4; ++nt)
        gxr[nt] = *(const v4f*)(gp + (size_t)(nt * HH + col) * BB);
    }
  }

  if (LAYER == 1 && t1 < TT) {  // phased save
#pragma unroll
    for (int r = 0; r < 4; ++r) {
      const size_t ix = ((size_t)d * BB + (w * 16 + hp * 4 + r)) * HH + col;
      cst[ix] = c_reg[r];
      cst[(size_t)2 * BB * HH + ix] = h_reg[r];
    }
  }
  if (LAYER == 1 && d == 0 && t1 == TT) {  // fwd final state (frozen at t=L-1)
#pragma unroll
    for (int r = 0; r < 4; ++r) feat[(w * 16 + hp * 4 + r) * 512 + col] = h_reg[r];
  }
}

// ---------------- head ----------------
__global__ void head_fc1(const float* __restrict__ feat, const float* __restrict__ w,
                         const float* __restrict__ b, float* __restrict__ y) {
  const int bb = blockIdx.x, o = threadIdx.x;
  __shared__ float f[512];
  f[o] = feat[bb * 512 + o];
  f[o + 256] = feat[bb * 512 + 256 + o];
  __syncthreads();
  float acc = b[o];
  const float* wr = w + (size_t)o * 512;
  for (int i = 0; i < 512; ++i) acc = fmaf(f[i], wr[i], acc);
  y[bb * 256 + o] = fmaxf(acc, 0.f);
}
__global__ void head_bn(const float* __restrict__ y, const float* __restrict__ gamma,
                        const float* __restrict__ beta, float* __restrict__ ss) {
  const int o = threadIdx.x;
  float s1 = 0.f, s2 = 0.f;
  for (int b = 0; b < 64; ++b) { const float v = y[b * 256 + o]; s1 += v; s2 += v * v; }
  const float mean = s1 * 0.015625f;
  const float var = s2 * 0.015625f - mean * mean;
  const float sc = gamma[o] * __builtin_amdgcn_rsqf(var + 1e-5f);
  ss[o] = sc;
  ss[256 + o] = beta[o] - mean * sc;
}
__global__ void head_out(const float* __restrict__ y, const float* __restrict__ ss,
                         const float* __restrict__ w, const float* __restrict__ b,
                         float* __restrict__ out) {
  const int bb = blockIdx.x, q = threadIdx.x;
  __shared__ float z[256];
  z[q] = y[bb * 256 + q] * ss[q] + ss[256 + q];
  __syncthreads();
  if (q < 196) {
    float acc = b[q];
    const float* wr = w + (size_t)q * 256;
    for (int o = 0; o < 256; ++o) acc = fmaf(z[o], wr[o], acc);
    out[bb * 196 + q] = acc;
  }
}

extern "C" void kernel_launch(void* const* d_in, const int* in_sizes, int n_in,
                              void* d_out, int out_size, void* d_ws, size_t ws_size,
                              hipStream_t stream) {
  const float* x       = (const float*)d_in[0];
  const int* lengths   = (const int*)d_in[1];
  const float* W_ih_l0 = (const float*)d_in[2];
  const float* W_hh_l0 = (const float*)d_in[3];
  const float* b_ih_l0 = (const float*)d_in[4];
  const float* b_hh_l0 = (const float*)d_in[5];
  const float* W_ih_l1 = (const float*)d_in[6];
  const float* W_hh_l1 = (const float*)d_in[7];
  const float* b_ih_l1 = (const float*)d_in[8];
  const float* b_hh_l1 = (const float*)d_in[9];
  const float* fc1_w   = (const float*)d_in[10];
  const float* fc1_b   = (const float*)d_in[11];
  const float* bn_g    = (const float*)d_in[12];
  const float* bn_b    = (const float*)d_in[13];
  const float* fco_w   = (const float*)d_in[14];
  const float* fco_b   = (const float*)d_in[15];
  float* out = (float*)d_out;

  char* ws = (char*)d_ws;
  size_t off = 0;
  auto alloc = [&](size_t sz) { char* p = ws + off; off += (sz + 255) & ~(size_t)255; return p; };
  int* prog0       = (int*)alloc(2 * NSL * 16 * 4);   // per-WG progress words, 64B padded
  int* prog1       = (int*)alloc(2 * NSL * 16 * 4);
  float* feat      = (float*)alloc(BB * 512 * 4);
  float* ybuf      = (float*)alloc(BB * 256 * 4);
  float* ss        = (float*)alloc(2 * 256 * 4);
  short* h_ex      = (short*)alloc(2 * 2 * BB * HH * 2);
  float* cst       = (float*)alloc(2 * 2 * BB * HH * 4);              // c|h phase carry
  _Float16* w1h    = (_Float16*)alloc((size_t)2 * 1024 * 512 * 2);
  _Float16* h1     = (_Float16*)alloc((size_t)TT * 2 * BB * HH * 2);  // [t][d][b][256]
  size_t xpad_off  = off;
  _Float16* xpad   = (_Float16*)alloc((size_t)2 * TT * BB * 32 * 2);
  // base total ~78 MB

  if (off > ws_size) {  // distinct signal: NaN output instead of zeros
    hipMemsetAsync(d_out, 0xFF, (size_t)out_size * 4, stream);
    return;
  }

  // gx buffer (fp32) overlays xpad (dead after scan0) and all tail space.
  // CH = t-steps per phase that fit; < TCHUNK -> in-scan fallback.
  const size_t perT = (size_t)2 * G4H * BB * 4;  // 512 KB per t-step (both dirs)
  size_t gx_avail = ws_size - xpad_off;
  int CH = (int)(gx_avail / perT);
  if (CH > TT) CH = TT;
  CH &= ~(TCHUNK - 1);
  float* gxbuf = (float*)(ws + xpad_off);

  // prog0 | prog1 contiguous: one memset to -1
  hipMemsetAsync(prog0, 0xFF, 2 * 2 * NSL * 16 * 4, stream);

  prep_w1<<<(2 * 1024 * 512 + 255) / 256, 256, 0, stream>>>(W_ih_l1, w1h);
  prep_x<<<(2 * TT * BB * 32 + 255) / 256, 256, 0, stream>>>(x, lengths, xpad);

  lstm_scan<0, 0><<<128, 256, 0, stream>>>(W_hh_l0, W_ih_l0, b_ih_l0, b_hh_l0, xpad,
                                           nullptr, nullptr, h1, nullptr, h_ex, prog0,
                                           lengths, nullptr, 0, TT);
  if (CH >= TCHUNK) {
    const int np = (TT + CH - 1) / CH;
    for (int k = 0; k < np; ++k) {
      const int t0 = k * CH;
      const int t1 = (t0 + CH < TT) ? (t0 + CH) : TT;
      gx1_gemm<<<2 * 16 * ((t1 - t0) / TCHUNK), 256, 0, stream>>>(h1, w1h, lengths,
                                                                  gxbuf, t0);
      lstm_scan<1, 1><<<128, 256, 0, stream>>>(W_hh_l1, nullptr, b_ih_l1, b_hh_l1,
                                               nullptr, gxbuf, h1, nullptr, feat, h_ex,
                                               prog1, lengths, cst, t0, t1);
    }
  } else {  // fallback: in-scan gate GEMM (w1h passed through the Wih0 slot)
    lstm_scan<1, 0><<<128, 256, 0, stream>>>(W_hh_l1, (const float*)w1h, b_ih_l1,
                                             b_hh_l1, nullptr, nullptr, h1, nullptr,
                                             feat, h_ex, prog1, lengths, cst, 0, TT);
  }

  head_fc1<<<64, 256, 0, stream>>>(feat, fc1_w, fc1_b, ybuf);
  head_bn<<<1, 256, 0, stream>>>(ybuf, bn_g, bn_b, ss);
  head_out<<<64, 256, 0, stream>>>(ybuf, ss, fco_w, fco_b, out);
}

// Round 7
// 8166.174 us; speedup vs baseline: 1.4059x; 1.0802x over previous
//
#include <hip/hip_runtime.h>
#include <stdint.h>

#define HH 256
#define BB 64
#define TT 1024
#define G4H 1024
#define NSL 16              // workgroups per direction (gate-split)
#define KC 16               // h-columns owned per WG
#define SPIN_LIM (1 << 19)  // per-wave cumulative spin budget (~0.2s worst) -> fast wrong answer, no hang
#define TCHUNK 64           // t-steps per gx1_gemm block

typedef _Float16 v8h __attribute__((ext_vector_type(8)));
typedef float v4f __attribute__((ext_vector_type(4)));

union HFP8 { _Float16 h[8]; v8h v; };
union ULL2F { unsigned long long u[2]; v8h v; };

__device__ __forceinline__ float fsig(float x) {
  float e = __builtin_amdgcn_exp2f(x * -1.44269504f);
  return __builtin_amdgcn_rcpf(1.f + e);
}
__device__ __forceinline__ float ftanh(float x) {
  float e = __builtin_amdgcn_exp2f(x * 2.88539008f);
  return 1.f - 2.f * __builtin_amdgcn_rcpf(e + 1.f);
}

// ---------------- prep kernels ----------------
__global__ void prep_w1(const float* __restrict__ w, _Float16* __restrict__ wh) {
  int i = blockIdx.x * 256 + threadIdx.x;
  if (i < 2 * 1024 * 512) wh[i] = (_Float16)w[i];
}

// xpad[d][t][b][32] fp16 : x (or reversed x) padded to K=32
__global__ void prep_x(const float* __restrict__ x, const int* __restrict__ lengths,
                       _Float16* __restrict__ xpad) {
  int i = blockIdx.x * 256 + threadIdx.x;
  if (i >= 2 * TT * BB * 32) return;
  int k = i & 31, bb = (i >> 5) & 63, t = (i >> 11) & 1023, d = (i >> 21) & 1;
  float v = 0.f;
  if (k < 3) {
    int L = lengths[bb];
    int rt = (d == 0) ? t : ((t < L) ? (L - 1 - t) : t);
    v = x[((size_t)bb * TT + rt) * 3 + k];
  }
  xpad[i] = (_Float16)v;
}

// ---------------- layer-1 gate-init GEMM (hoisted, PHASED, fp32 out) ----------------
// h1 layout [t][d][b][256] in SCAN-STEP order (bwd not re-reversed). Input row of
// layer-1 dir d at scan step t = [h1[p][0][b], h1[s][1][b]] with
// p = (d==0)? t : ((t<L)? L-1-t : t),  s = (p<L)? L-1-p : p   (for d==1, s==t).
// Output gxq[tloc][d][gate][b] fp32 for t in [t0, t0 + 64*gridT).
__global__ __launch_bounds__(256, 1)
void gx1_gemm(const _Float16* __restrict__ h1, const _Float16* __restrict__ w1h,
              const int* __restrict__ lengths, float* __restrict__ gxq, int t0) {
  const int blk = blockIdx.x;
  const int d = blk & 1;
  const int g = (blk >> 1) & 15;
  const int tc = blk >> 5;
  const int tid = threadIdx.x;
  const int w = tid >> 6;
  const int l = tid & 63;
  const int l15 = l & 15;
  const int hp = l >> 4;
  const int col = g * KC + l15;

  // B-fragments: W_ih_l1 rows {nt*256+col}, K=512 (k<256 fwd half, k>=256 bwd half)
  v8h wf[16][4];
#pragma unroll
  for (int kt = 0; kt < 16; ++kt)
#pragma unroll
    for (int nt = 0; nt < 4; ++nt)
      wf[kt][nt] =
          *(const v8h*)(w1h + ((size_t)d * G4H + nt * HH + col) * 512 + kt * 32 + hp * 8);

  const int b = w * 16 + l15;  // this lane's A-row (batch)
  const int L = lengths[b];

  for (int i = 0; i < TCHUNK; ++i) {
    const int t = t0 + tc * TCHUNK + i;
    const int tloc = t - t0;
    const int p = (d == 0) ? t : ((t < L) ? (L - 1 - t) : t);
    const int s = (p < L) ? (L - 1 - p) : p;
    const _Float16* afwd = h1 + (((size_t)p * 2 + 0) * BB + b) * HH + hp * 8;
    const _Float16* abwd = h1 + (((size_t)s * 2 + 1) * BB + b) * HH + hp * 8;
    v4f acc[4];
#pragma unroll
    for (int nt = 0; nt < 4; ++nt) acc[nt] = v4f{0.f, 0.f, 0.f, 0.f};
#pragma unroll
    for (int kt = 0; kt < 8; ++kt) {
      const v8h a = *(const v8h*)(afwd + kt * 32);
#pragma unroll
      for (int nt = 0; nt < 4; ++nt)
        acc[nt] = __builtin_amdgcn_mfma_f32_16x16x32_f16(a, wf[kt][nt], acc[nt], 0, 0, 0);
    }
#pragma unroll
    for (int kt = 8; kt < 16; ++kt) {
      const v8h a = *(const v8h*)(abwd + (kt - 8) * 32);
#pragma unroll
      for (int nt = 0; nt < 4; ++nt)
        acc[nt] = __builtin_amdgcn_mfma_f32_16x16x32_f16(a, wf[kt][nt], acc[nt], 0, 0, 0);
    }
    // C-frag: row(b') = w*16+hp*4+r, col(gate) = nt*256+col -> one 16B store per nt
    float* drow = gxq + (((size_t)tloc * 2 + d) * G4H) * (size_t)BB + w * 16 + hp * 4;
#pragma unroll
    for (int nt = 0; nt < 4; ++nt)
      *(v4f*)(drow + (size_t)(nt * HH + col) * BB) = acc[nt];
  }
}

// ---------------- persistent gate-split LSTM scan (per-wave sync planes) ----------------
// grid 128; active blocks: (blk&7)<2 -> dir d = blk&7, slice g = blk>>3 (0..15).
// PLANE FACTORIZATION: wave w of every WG writes h-rows [16w,16w+16) and reads ONLY
// those rows -> 4 independent sync planes. Publish/poll is per (WG, wave):
//   prog[d][g][w] (64B-padded). A wave: reads hex(t-1) -> MFMA -> gates -> 4 agent
//   h-stores -> s_waitcnt vmcnt(0) (per-wave, vouches its own stores) -> publish.
//   It polls the 16 words {g'=0..15, its w} of its plane. NO __syncthreads in loop.
// Parity safety (plane-closed): writer at t+1 stores parity (t+1)&1 only after its
// plane peers published t, which implies they finished reading parity (t-1).
// All memory ops are agent-scope relaxed atomics (round-6-proven visibility).
// Watchdog: per-wave cumulative guard; a timed-out wave breaks, starved peers
// time out too -> fast wrong answer, never a hang (no barriers to strand).
// GX==1: gate-init from fp32 gxq, register-prefetched one step ahead; the add is
// placed AFTER the recurrent MFMAs so its load latency hides under poll+hex+MFMA.
// Phasing (LAYER 1): [t0,t1) window; c/h carried via cst across launches.
template <int LAYER, int GX>
__global__ __launch_bounds__(256, 1)
void lstm_scan(const float* __restrict__ Whh, const float* __restrict__ Wih0,
               const float* __restrict__ bih, const float* __restrict__ bhh,
               const _Float16* __restrict__ xpad, const float* __restrict__ gxq,
               const _Float16* __restrict__ h1in,
               _Float16* __restrict__ h1out, float* __restrict__ feat,
               short* __restrict__ h_ex, int* __restrict__ prog,
               const int* __restrict__ lengths, float* __restrict__ cst,
               int t0, int t1) {
  const int blk = blockIdx.x;
  if ((blk & 7) >= 2) return;
  const int d = blk & 7;
  const int g = blk >> 3;
  const int tid = threadIdx.x;
  const int w = tid >> 6;        // wave id = batch tile = sync plane
  const int l = tid & 63;
  const int l15 = l & 15;
  const int hp = l >> 4;
  const int col = g * KC + l15;  // owned h-column

  // persistent W_hh fragments (B-operand layout: lane = W[j=nt*256+col][k=kt*32+hp*8+e])
  v8h wfrag[8][4];
#pragma unroll
  for (int kt = 0; kt < 8; ++kt) {
#pragma unroll
    for (int nt = 0; nt < 4; ++nt) {
      const int j = nt * HH + col;
      const float* src = Whh + ((size_t)d * G4H + j) * HH + kt * 32 + hp * 8;
      HFP8 p;
#pragma unroll
      for (int e = 0; e < 8; ++e) p.h[e] = (_Float16)src[e];
      wfrag[kt][nt] = p.v;
    }
  }
  float bias[4];
#pragma unroll
  for (int nt = 0; nt < 4; ++nt)
    bias[nt] = bih[d * G4H + nt * HH + col] + bhh[d * G4H + nt * HH + col];

  v8h xfrag[4];  // layer 0: W_ih_l0 (K=3 padded to 32)
  if (LAYER == 0) {
#pragma unroll
    for (int nt = 0; nt < 4; ++nt) {
      const int j = nt * HH + col;
      HFP8 p;
#pragma unroll
      for (int e = 0; e < 8; ++e) {
        const int kl = hp * 8 + e;
        p.h[e] = (kl < 3) ? (_Float16)Wih0[((size_t)d * G4H + j) * 3 + kl] : (_Float16)0.f;
      }
      xfrag[nt] = p.v;
    }
  }
  v8h w1frag[16][4];  // layer-1 fallback: W_ih_l1 slice, B-fragments (K=512)
  if (LAYER == 1 && GX == 0) {
#pragma unroll
    for (int kt = 0; kt < 16; ++kt)
#pragma unroll
      for (int nt = 0; nt < 4; ++nt)
        w1frag[kt][nt] =
            *(const v8h*)((const _Float16*)Wih0 +  // reuse Wih0 slot for w1h
                          ((size_t)d * G4H + nt * HH + col) * 512 + kt * 32 + hp * 8);
  }

  int Lr[4];
#pragma unroll
  for (int r = 0; r < 4; ++r) Lr[r] = lengths[w * 16 + hp * 4 + r];
  const int bb = w * 16 + l15;
  const int La = lengths[bb];  // lane's A-row length (fallback path)

  float c_reg[4] = {0.f, 0.f, 0.f, 0.f};
  float h_reg[4] = {0.f, 0.f, 0.f, 0.f};
  if (LAYER == 1 && t0 > 0) {  // phased restore (written by previous launch)
#pragma unroll
    for (int r = 0; r < 4; ++r) {
      const size_t ix = ((size_t)d * BB + (w * 16 + hp * 4 + r)) * HH + col;
      c_reg[r] = cst[ix];
      h_reg[r] = cst[(size_t)2 * BB * HH + ix];
    }
  }

  short* hex_d = h_ex + (size_t)d * 2 * BB * HH;   // parity-double-buffered
  int* prg = prog + d * NSL * 4 * 16;              // [g][w] words, 64B padded
  int guard = 0;

  // prefetch gate-init input for first step
  v8h xr;      // layer 0
  v4f gxr[4];  // layer 1 (GX path, fp32)
  if (LAYER == 0) {
    xr = *(const v8h*)(xpad + (((size_t)d * TT + t0) * BB + bb) * 32 + hp * 8);
  } else if (GX) {
    const float* gp = gxq + ((size_t)0 * 2 + d) * G4H * (size_t)BB + w * 16 + hp * 4;
#pragma unroll
    for (int nt = 0; nt < 4; ++nt)
      gxr[nt] = *(const v4f*)(gp + (size_t)(nt * HH + col) * BB);
  }

  for (int t = t0; t < t1; ++t) {
    v4f acc[4];
#pragma unroll
    for (int nt = 0; nt < 4; ++nt) acc[nt] = v4f{bias[nt], bias[nt], bias[nt], bias[nt]};

    if (LAYER == 1 && GX == 0) {
      // fallback in-scan gate GEMM (memory-fed; keep BEFORE the poll to overlap)
      const int p = (d == 0) ? t : ((t < La) ? (La - 1 - t) : t);
      const int s = (p < La) ? (La - 1 - p) : p;
      const _Float16* afwd = h1in + (((size_t)p * 2 + 0) * BB + bb) * HH + hp * 8;
      const _Float16* abwd = h1in + (((size_t)s * 2 + 1) * BB + bb) * HH + hp * 8;
#pragma unroll
      for (int kt = 0; kt < 8; ++kt) {
        const v8h a = *(const v8h*)(afwd + kt * 32);
#pragma unroll
        for (int nt = 0; nt < 4; ++nt)
          acc[nt] = __builtin_amdgcn_mfma_f32_16x16x32_f16(a, w1frag[kt][nt], acc[nt], 0, 0, 0);
      }
#pragma unroll
      for (int kt = 8; kt < 16; ++kt) {
        const v8h a = *(const v8h*)(abwd + (kt - 8) * 32);
#pragma unroll
        for (int nt = 0; nt < 4; ++nt)
          acc[nt] = __builtin_amdgcn_mfma_f32_16x16x32_f16(a, w1frag[kt][nt], acc[nt], 0, 0, 0);
      }
    }

    if (t > 0) {
      // per-wave poll of this plane's 16 words {g'=l, w}
      int ok = 1;
      for (;;) {
        int v = (l < NSL)
                    ? __hip_atomic_load(&prg[(l * 4 + w) * 16], __ATOMIC_RELAXED,
                                        __HIP_MEMORY_SCOPE_AGENT)
                    : (t - 1);
        if (__all(v >= t - 1)) break;
        __builtin_amdgcn_s_sleep(1);
        if (++guard > SPIN_LIM) { ok = 0; break; }
      }
      if (!ok) break;  // wave-uniform; starved peers will also time out. No hang.

      // A-fragments from exchange buffer: 16 x 8B relaxed-atomic loads (own plane rows)
      const unsigned long long* src =
          (const unsigned long long*)(hex_d + ((t - 1) & 1) * BB * HH);
      const int base = (w * 16 + l15) * 64 + hp * 2;  // ull index into 256-col row
      unsigned long long fr[16];
#pragma unroll
      for (int kt = 0; kt < 8; ++kt) {
        fr[2 * kt] = __hip_atomic_load(src + base + kt * 8, __ATOMIC_RELAXED,
                                       __HIP_MEMORY_SCOPE_AGENT);
        fr[2 * kt + 1] = __hip_atomic_load(src + base + kt * 8 + 1, __ATOMIC_RELAXED,
                                           __HIP_MEMORY_SCOPE_AGENT);
      }
#pragma unroll
      for (int kt = 0; kt < 8; ++kt) {
        ULL2F u;
        u.u[0] = fr[2 * kt];
        u.u[1] = fr[2 * kt + 1];
#pragma unroll
        for (int nt = 0; nt < 4; ++nt)
          acc[nt] = __builtin_amdgcn_mfma_f32_16x16x32_f16(u.v, wfrag[kt][nt], acc[nt], 0, 0, 0);
      }
    }

    // gate-init contribution AFTER the recurrent MFMAs: its prefetch-load waitcnt
    // hides under poll+hex+MFMA instead of blocking before the poll.
    if (LAYER == 0) {
#pragma unroll
      for (int nt = 0; nt < 4; ++nt)
        acc[nt] = __builtin_amdgcn_mfma_f32_16x16x32_f16(xr, xfrag[nt], acc[nt], 0, 0, 0);
    } else if (GX) {
#pragma unroll
      for (int nt = 0; nt < 4; ++nt) acc[nt] += gxr[nt];
    }

    short* dst = hex_d + (t & 1) * BB * HH;
#pragma unroll
    for (int r = 0; r < 4; ++r) {
      const int m = w * 16 + hp * 4 + r;
      const float iv = acc[0][r], fv = acc[1][r], gv = acc[2][r], ov = acc[3][r];
      const float cn = fsig(fv) * c_reg[r] + fsig(iv) * ftanh(gv);
      const float hn = fsig(ov) * ftanh(cn);
      const bool valid = t < Lr[r];
      if (valid) { c_reg[r] = cn; h_reg[r] = hn; }
      union { _Float16 f; short s; } hb;
      hb.f = (_Float16)h_reg[r];
      __hip_atomic_store(&dst[m * HH + col], hb.s, __ATOMIC_RELAXED, __HIP_MEMORY_SCOPE_AGENT);
      if (LAYER == 1 && d == 1 && t == 0) {
        feat[m * 512 + HH + col] = h_reg[r];  // bwd out at orig t=L-1 == first bwd step
      }
    }
    // per-wave: my 4 h-stores are at the coherence point -> publish my plane word
    asm volatile("s_waitcnt vmcnt(0)" ::: "memory");
    if (l == 0)
      __hip_atomic_store(&prg[(g * 4 + w) * 16], t, __ATOMIC_RELAXED,
                         __HIP_MEMORY_SCOPE_AGENT);

    // ---- post-publish (off the protocol critical path) ----
    if (LAYER == 0) {  // h1 store, coalesced [t][d][b][256], scan-step order
      _Float16* hr = h1out + (((size_t)t * 2 + d) * BB) * HH + col;
#pragma unroll
      for (int r = 0; r < 4; ++r)
        hr[(size_t)(w * 16 + hp * 4 + r) * HH] =
            (t < Lr[r]) ? (_Float16)h_reg[r] : (_Float16)0.f;
    }
    // next-step gate-init prefetch (flies during the next poll window)
    const int tp = (t + 1 < t1) ? t + 1 : t;
    if (LAYER == 0) {
      xr = *(const v8h*)(xpad + (((size_t)d * TT + tp) * BB + bb) * 32 + hp * 8);
    } else if (GX) {
      const float* gp =
          gxq + (((size_t)(tp - t0) * 2 + d) * G4H) * (size_t)BB + w * 16 + hp * 4;
#pragma unroll
      for (int nt = 0; nt < 4; ++nt)
        gxr[nt] = *(const v4f*)(gp + (size_t)(nt * HH + col) * BB);
    }
  }

  if (LAYER == 1 && t1 < TT) {  // phased save
#pragma unroll
    for (int r = 0; r < 4; ++r) {
      const size_t ix = ((size_t)d * BB + (w * 16 + hp * 4 + r)) * HH + col;
      cst[ix] = c_reg[r];
      cst[(size_t)2 * BB * HH + ix] = h_reg[r];
    }
  }
  if (LAYER == 1 && d == 0 && t1 == TT) {  // fwd final state (frozen at t=L-1)
#pragma unroll
    for (int r = 0; r < 4; ++r) feat[(w * 16 + hp * 4 + r) * 512 + col] = h_reg[r];
  }
}

// ---------------- head ----------------
__global__ void head_fc1(const float* __restrict__ feat, const float* __restrict__ w,
                         const float* __restrict__ b, float* __restrict__ y) {
  const int bb = blockIdx.x, o = threadIdx.x;
  __shared__ float f[512];
  f[o] = feat[bb * 512 + o];
  f[o + 256] = feat[bb * 512 + 256 + o];
  __syncthreads();
  float acc = b[o];
  const float* wr = w + (size_t)o * 512;
  for (int i = 0; i < 512; ++i) acc = fmaf(f[i], wr[i], acc);
  y[bb * 256 + o] = fmaxf(acc, 0.f);
}
__global__ void head_bn(const float* __restrict__ y, const float* __restrict__ gamma,
                        const float* __restrict__ beta, float* __restrict__ ss) {
  const int o = threadIdx.x;
  float s1 = 0.f, s2 = 0.f;
  for (int b = 0; b < 64; ++b) { const float v = y[b * 256 + o]; s1 += v; s2 += v * v; }
  const float mean = s1 * 0.015625f;
  const float var = s2 * 0.015625f - mean * mean;
  const float sc = gamma[o] * __builtin_amdgcn_rsqf(var + 1e-5f);
  ss[o] = sc;
  ss[256 + o] = beta[o] - mean * sc;
}
__global__ void head_out(const float* __restrict__ y, const float* __restrict__ ss,
                         const float* __restrict__ w, const float* __restrict__ b,
                         float* __restrict__ out) {
  const int bb = blockIdx.x, q = threadIdx.x;
  __shared__ float z[256];
  z[q] = y[bb * 256 + q] * ss[q] + ss[256 + q];
  __syncthreads();
  if (q < 196) {
    float acc = b[q];
    const float* wr = w + (size_t)q * 256;
    for (int o = 0; o < 256; ++o) acc = fmaf(z[o], wr[o], acc);
    out[bb * 196 + q] = acc;
  }
}

extern "C" void kernel_launch(void* const* d_in, const int* in_sizes, int n_in,
                              void* d_out, int out_size, void* d_ws, size_t ws_size,
                              hipStream_t stream) {
  const float* x       = (const float*)d_in[0];
  const int* lengths   = (const int*)d_in[1];
  const float* W_ih_l0 = (const float*)d_in[2];
  const float* W_hh_l0 = (const float*)d_in[3];
  const float* b_ih_l0 = (const float*)d_in[4];
  const float* b_hh_l0 = (const float*)d_in[5];
  const float* W_ih_l1 = (const float*)d_in[6];
  const float* W_hh_l1 = (const float*)d_in[7];
  const float* b_ih_l1 = (const float*)d_in[8];
  const float* b_hh_l1 = (const float*)d_in[9];
  const float* fc1_w   = (const float*)d_in[10];
  const float* fc1_b   = (const float*)d_in[11];
  const float* bn_g    = (const float*)d_in[12];
  const float* bn_b    = (const float*)d_in[13];
  const float* fco_w   = (const float*)d_in[14];
  const float* fco_b   = (const float*)d_in[15];
  float* out = (float*)d_out;

  char* ws = (char*)d_ws;
  size_t off = 0;
  auto alloc = [&](size_t sz) { char* p = ws + off; off += (sz + 255) & ~(size_t)255; return p; };
  int* prog0       = (int*)alloc(2 * NSL * 4 * 16 * 4);  // per-(WG,wave) words, 64B padded
  int* prog1       = (int*)alloc(2 * NSL * 4 * 16 * 4);
  float* feat      = (float*)alloc(BB * 512 * 4);
  float* ybuf      = (float*)alloc(BB * 256 * 4);
  float* ss        = (float*)alloc(2 * 256 * 4);
  short* h_ex      = (short*)alloc(2 * 2 * BB * HH * 2);
  float* cst       = (float*)alloc(2 * 2 * BB * HH * 4);              // c|h phase carry
  _Float16* w1h    = (_Float16*)alloc((size_t)2 * 1024 * 512 * 2);
  _Float16* h1     = (_Float16*)alloc((size_t)TT * 2 * BB * HH * 2);  // [t][d][b][256]
  size_t xpad_off  = off;
  _Float16* xpad   = (_Float16*)alloc((size_t)2 * TT * BB * 32 * 2);
  // base total ~78 MB

  if (off > ws_size) {  // distinct signal: NaN output instead of zeros
    hipMemsetAsync(d_out, 0xFF, (size_t)out_size * 4, stream);
    return;
  }

  // gx buffer (fp32) overlays xpad (dead after scan0) and all tail space.
  // CH = t-steps per phase that fit; < TCHUNK -> in-scan fallback.
  const size_t perT = (size_t)2 * G4H * BB * 4;  // 512 KB per t-step (both dirs)
  size_t gx_avail = ws_size - xpad_off;
  int CH = (int)(gx_avail / perT);
  if (CH > TT) CH = TT;
  CH &= ~(TCHUNK - 1);
  float* gxbuf = (float*)(ws + xpad_off);

  // prog0 | prog1 contiguous: one memset to -1
  hipMemsetAsync(prog0, 0xFF, 2 * 2 * NSL * 4 * 16 * 4, stream);

  prep_w1<<<(2 * 1024 * 512 + 255) / 256, 256, 0, stream>>>(W_ih_l1, w1h);
  prep_x<<<(2 * TT * BB * 32 + 255) / 256, 256, 0, stream>>>(x, lengths, xpad);

  lstm_scan<0, 0><<<128, 256, 0, stream>>>(W_hh_l0, W_ih_l0, b_ih_l0, b_hh_l0, xpad,
                                           nullptr, nullptr, h1, nullptr, h_ex, prog0,
                                           lengths, nullptr, 0, TT);
  if (CH >= TCHUNK) {
    const int np = (TT + CH - 1) / CH;
    for (int k = 0; k < np; ++k) {
      const int t0 = k * CH;
      const int t1 = (t0 + CH < TT) ? (t0 + CH) : TT;
      gx1_gemm<<<2 * 16 * ((t1 - t0) / TCHUNK), 256, 0, stream>>>(h1, w1h, lengths,
                                                                  gxbuf, t0);
      lstm_scan<1, 1><<<128, 256, 0, stream>>>(W_hh_l1, nullptr, b_ih_l1, b_hh_l1,
                                               nullptr, gxbuf, h1, nullptr, feat, h_ex,
                                               prog1, lengths, cst, t0, t1);
    }
  } else {  // fallback: in-scan gate GEMM (w1h passed through the Wih0 slot)
    lstm_scan<1, 0><<<128, 256, 0, stream>>>(W_hh_l1, (const float*)w1h, b_ih_l1,
                                             b_hh_l1, nullptr, nullptr, h1, nullptr,
                                             feat, h_ex, prog1, lengths, cst, 0, TT);
  }

  head_fc1<<<64, 256, 0, stream>>>(feat, fc1_w, fc1_b, ybuf);
  head_bn<<<1, 256, 0, stream>>>(ybuf, bn_g, bn_b, ss);
  head_out<<<64, 256, 0, stream>>>(ybuf, ss, fco_w, fco_b, out);
}